// Round 11
// baseline (3493.422 us; speedup 1.0000x reference)
//
#include <hip/hip_runtime.h>

typedef unsigned short u16;
typedef __attribute__((ext_vector_type(8))) short s16x8;
typedef __attribute__((ext_vector_type(4))) float f32x4;

#define NB    1024
#define MTOK  64
#define DM    512
#define NHD   8
#define HDIM  64
#define FFD   2048
#define NOBJ  8192
#define NTRI  10240

__device__ __forceinline__ float bfu2f(u16 u) { return __uint_as_float(((unsigned)u) << 16); }
__device__ __forceinline__ u16 f2bfu(float f) {
  unsigned u = __float_as_uint(f);
  u += 0x7FFFu + ((u >> 16) & 1u);
  return (u16)(u >> 16);
}
// Branch-free gelu: erf via Abramowitz-Stegun 7.1.26 (|err|<=1.5e-7, far
// below bf16 rounding; absmax verified unchanged rounds 7-10). ~15
// straight-line ops incl. one v_exp_f32.
__device__ __forceinline__ float gelu_exact(float x) {
  float z = fabsf(x) * 0.70710678118654752440f;
  float t = __builtin_amdgcn_rcpf(__builtin_fmaf(0.3275911f, z, 1.0f));
  float p = t * (0.254829592f +
            t * (-0.284496736f +
            t * (1.421413741f +
            t * (-1.453152027f +
            t * 1.061405429f))));
  float e = 1.0f - p * __expf(-z * z);
  e = copysignf(e, x);
  return 0.5f * x * (1.0f + e);
}

// ---------------- weight prep: f32 [R][C] -> bf16 [C][R] ----------------
__global__ void transpose_dd_kernel(const float* __restrict__ wq, const float* __restrict__ wk,
                                    const float* __restrict__ wv, const float* __restrict__ wo,
                                    u16* __restrict__ wqkvt, u16* __restrict__ wot) {
  __shared__ u16 tile[32][33];
  int l = blockIdx.z >> 2, w = blockIdx.z & 3;
  const float* src = (w == 0 ? wq : w == 1 ? wk : w == 2 ? wv : wo) + (size_t)l * 262144;
  u16* dst = (w < 3) ? (wqkvt + (size_t)l * 786432 + (size_t)w * 262144) : (wot + (size_t)l * 262144);
  int c0 = blockIdx.x * 32, r0 = blockIdx.y * 32;
  int tx = threadIdx.x, ty = threadIdx.y;
  #pragma unroll
  for (int i = 0; i < 4; i++)
    tile[ty + i * 8][tx] = f2bfu(src[(size_t)(r0 + ty + i * 8) * 512 + c0 + tx]);
  __syncthreads();
  #pragma unroll
  for (int i = 0; i < 4; i++)
    dst[(size_t)(c0 + ty + i * 8) * 512 + r0 + tx] = tile[tx][ty + i * 8];
}

__global__ void transpose_gen_kernel(const float* __restrict__ src, u16* __restrict__ dst,
                                     int R, int C) {
  __shared__ u16 tile[32][33];
  size_t mat = blockIdx.z;
  const float* s = src + mat * (size_t)R * C;
  u16* d = dst + mat * (size_t)R * C;
  int c0 = blockIdx.x * 32, r0 = blockIdx.y * 32;
  int tx = threadIdx.x, ty = threadIdx.y;
  #pragma unroll
  for (int i = 0; i < 4; i++)
    tile[ty + i * 8][tx] = f2bfu(s[(size_t)(r0 + ty + i * 8) * C + c0 + tx]);
  __syncthreads();
  #pragma unroll
  for (int i = 0; i < 4; i++)
    d[(size_t)(c0 + ty + i * 8) * R + r0 + tx] = tile[tx][ty + i * 8];
}

__global__ void concat_bias_kernel(const float* __restrict__ bq, const float* __restrict__ bk,
                                   const float* __restrict__ bv, float* __restrict__ bqkv) {
  int i = blockIdx.x * 256 + threadIdx.x;  // < 4*1536
  int l = i / 1536, j = i - l * 1536;
  int w = j >> 9, d = j & 511;
  const float* s = (w == 0) ? bq : (w == 1 ? bk : bv);
  bqkv[i] = s[l * 512 + d];
}

// ---------------- first[b] = lower_bound(triple_to_img, b) ----------------
__global__ void first_kernel(const int* __restrict__ tti, int* __restrict__ first) {
  int b = threadIdx.x;  // 1024 threads
  int lo = 0, hi = NTRI;
  while (lo < hi) { int mid = (lo + hi) >> 1; if (tti[mid] < b) lo = mid + 1; else hi = mid; }
  first[b] = lo;
}

// ---------------- box MLP + embedding: obj_tok (f32) ----------------
__global__ __launch_bounds__(256) void boxmlp_kernel(
    const int* __restrict__ objs, const float* __restrict__ boxes,
    const float* __restrict__ bw1, const float* __restrict__ bb1,
    const float* __restrict__ blg, const float* __restrict__ blb,
    const float* __restrict__ bw2, const float* __restrict__ bb2,
    const float* __restrict__ obj_emb, float* __restrict__ obj_tok) {
  __shared__ float hbuf[16][512];
  int tid = threadIdx.x;
  int base = blockIdx.x * 16;
  for (int o = 0; o < 16; o++) {
    int obj = base + o;
    float b0 = boxes[obj * 4 + 0], b1 = boxes[obj * 4 + 1];
    float b2 = boxes[obj * 4 + 2], b3 = boxes[obj * 4 + 3];
    for (int d = tid; d < 512; d += 256)
      hbuf[o][d] = bb1[d] + b0 * bw1[d] + b1 * bw1[512 + d] + b2 * bw1[1024 + d] + b3 * bw1[1536 + d];
  }
  __syncthreads();
  int wave = tid >> 6, lane = tid & 63;
  for (int oo = 0; oo < 4; oo++) {
    int o = wave * 4 + oo;
    float v[8], s = 0.f, ss = 0.f;
    #pragma unroll
    for (int e = 0; e < 8; e++) { v[e] = hbuf[o][lane * 8 + e]; s += v[e]; ss += v[e] * v[e]; }
    for (int off = 32; off > 0; off >>= 1) { s += __shfl_xor(s, off); ss += __shfl_xor(ss, off); }
    float mean = s * (1.0f / 512.0f);
    float var = ss * (1.0f / 512.0f) - mean * mean;
    float rstd = rsqrtf(var + 1e-5f);
    #pragma unroll
    for (int e = 0; e < 8; e++) {
      int d = lane * 8 + e;
      float g = (v[e] - mean) * rstd * blg[d] + blb[d];
      hbuf[o][d] = gelu_exact(g);
    }
  }
  __syncthreads();
  float acc0[16], acc1[16];
  #pragma unroll
  for (int o = 0; o < 16; o++) { acc0[o] = 0.f; acc1[o] = 0.f; }
  int d0 = tid, d1 = tid + 256;
  for (int k = 0; k < 512; k += 4) {
    float w0[4], w1[4];
    #pragma unroll
    for (int kk = 0; kk < 4; kk++) { w0[kk] = bw2[(k + kk) * 512 + d0]; w1[kk] = bw2[(k + kk) * 512 + d1]; }
    #pragma unroll
    for (int o = 0; o < 16; o++) {
      float4 hv = *(const float4*)&hbuf[o][k];
      acc0[o] += hv.x * w0[0] + hv.y * w0[1] + hv.z * w0[2] + hv.w * w0[3];
      acc1[o] += hv.x * w1[0] + hv.y * w1[1] + hv.z * w1[2] + hv.w * w1[3];
    }
  }
  #pragma unroll
  for (int o = 0; o < 16; o++) {
    int obj = base + o;
    int e = objs[obj];
    obj_tok[(size_t)obj * 512 + d0] = acc0[o] + bb2[d0] + obj_emb[(size_t)e * 512 + d0];
    obj_tok[(size_t)obj * 512 + d1] = acc1[o] + bb2[d1] + obj_emb[(size_t)e * 512 + d1];
  }
}

// ---------------- scatter triples -> tokens (x) + mask ----------------
__global__ __launch_bounds__(128) void scatter_kernel(
    const int* __restrict__ triples, const int* __restrict__ tti,
    const int* __restrict__ first, const float* __restrict__ obj_tok,
    const float* __restrict__ pred_emb, float* __restrict__ x,
    unsigned char* __restrict__ maskb) {
  int t = blockIdx.x / 3, j = blockIdx.x - t * 3;
  int b = tti[t];
  int pos = t - first[b];
  int slot = pos * 3 + j;
  if (slot >= MTOK) return;
  int dst_row = b * MTOK + slot;
  int d = threadIdx.x * 4;
  float4 val;
  if (j == 1) {
    int p = triples[t * 3 + 1];
    val = *(const float4*)(pred_emb + (size_t)p * 512 + d);
  } else {
    int oi = triples[t * 3 + (j == 0 ? 0 : 2)];
    val = *(const float4*)(obj_tok + (size_t)oi * 512 + d);
  }
  *(float4*)(x + (size_t)dst_row * 512 + d) = val;
  if (threadIdx.x == 0) maskb[dst_row] = 1;
}

// ---------------- LayerNorm (f32 in) -> bf16 out ----------------
__global__ __launch_bounds__(256) void ln_kernel(
    const float* __restrict__ x, u16* __restrict__ out,
    const float* __restrict__ gg, const float* __restrict__ bb) {
  int row = blockIdx.x * 4 + (threadIdx.x >> 6);
  int lane = threadIdx.x & 63;
  const float* xr = x + (size_t)row * DM + lane * 8;
  float4 a = *(const float4*)xr;
  float4 c = *(const float4*)(xr + 4);
  float v[8] = {a.x, a.y, a.z, a.w, c.x, c.y, c.z, c.w};
  float s = 0.f, ss = 0.f;
  #pragma unroll
  for (int e = 0; e < 8; e++) { s += v[e]; ss += v[e] * v[e]; }
  for (int off = 32; off > 0; off >>= 1) { s += __shfl_xor(s, off); ss += __shfl_xor(ss, off); }
  float mean = s * (1.0f / 512.0f);
  float var = ss * (1.0f / 512.0f) - mean * mean;
  float rstd = rsqrtf(var + 1e-5f);
  int dbase = lane * 8;
  unsigned pk[4];
  #pragma unroll
  for (int p = 0; p < 4; p++) {
    float y0 = (v[2 * p] - mean) * rstd * gg[dbase + 2 * p] + bb[dbase + 2 * p];
    float y1 = (v[2 * p + 1] - mean) * rstd * gg[dbase + 2 * p + 1] + bb[dbase + 2 * p + 1];
    pk[p] = (unsigned)f2bfu(y0) | ((unsigned)f2bfu(y1) << 16);
  }
  uint4 o; o.x = pk[0]; o.y = pk[1]; o.z = pk[2]; o.w = pk[3];
  *(uint4*)(out + (size_t)row * DM + dbase) = o;
}

// ---------------- bf16 MFMA GEMM: per-mode-best epilogue + HOISTED ADDRESSING.
// Round-11: all rounds 6-10 epilogue variants left VALUBusy pinned at ~48%
// (even the epilogue-free round 9) -> the VALU cost is the K-LOOP's address
// arithmetic: 8 global_load_lds 64-bit mul chains ((m0+row)*K+k0+scol) per
// step, re-materialized each iteration (m98 histogram: 21 v_lshl_add_u64).
// Fix: precompute 8 staging src pointers, advance += 64 per K-step (one add
// each); precompute 4 loop-invariant LDS read base ptrs (i*1024/j*1024 fold
// into ds_read offset: immediates). +~24 VGPR (64->~90, < (256,4)'s 128 cap).
// Epilogues (round-10 measured-best per mode) unchanged:
//  MODE 0/2: SWAPPED operands -> direct uint2 stores [FF1 238->217]
//  MODE 1:   original operands -> coalesced LDS-roundtrip float4 RMW
// 128x128 tile, BK=64, single-buffered staging, 256 thr / 4 waves.
// C = A[MxK] @ Wt[NxK]^T (+bias)
// MODE 0: outb = bf16(acc+bias)  MODE 1: resid += acc+bias  MODE 2: outb = bf16(gelu(acc+bias))
template <int MODE>
__global__ __launch_bounds__(256, 4) void gemm_kernel(
    const u16* __restrict__ A, const u16* __restrict__ Wt,
    const float* __restrict__ bias, float* __restrict__ resid,
    u16* __restrict__ outb, int M, int N, int K, int nb_n) {
  // MODE 1 needs 64x132 f32 = 33.8KB for the epilogue roundtrip; others 32KB.
  __shared__ __align__(16) u16 smem[MODE == 1 ? 17408 : 16384];
  u16* aT = smem;          // 128x64 u16 = 16 KB
  u16* bT = smem + 8192;   // 128x64 u16 = 16 KB
  const int tid = threadIdx.x;
  const int wave = tid >> 6, lane = tid & 63;
  const int l15 = lane & 15, q4 = lane >> 4;
  const int wm = (wave >> 1) * 64, wn = (wave & 1) * 64;

  const int L = blockIdx.x;
  const int xg = L & 7, g = L >> 3;
  const int cblk = g % nb_n;
  const int pblk = xg + 8 * (g / nb_n);
  const int m0 = pblk * 128;
  const int n0 = cblk * 128;

  const int lrow = lane >> 3;                       // 0..7
  const int scol = (((lane & 7) ^ lrow) << 3);      // swizzled source col
  const int swz = l15 & 7;                          // fragment-read swizzle

  // ---- hoisted staging source pointers (advance 64 u16 = 128B per K-step)
  const u16* aSrc[4];
  const u16* bSrc[4];
  #pragma unroll
  for (int i = 0; i < 4; i++) {
    const int chunk = i * 4 + wave;
    const int row = chunk * 8 + lrow;
    aSrc[i] = A + (size_t)(m0 + row) * K + scol;
    bSrc[i] = Wt + (size_t)(n0 + row) * K + scol;
  }
  // ---- hoisted LDS staging dest offsets (loop-invariant)
  u16* aDst[4];
  u16* bDst[4];
  #pragma unroll
  for (int i = 0; i < 4; i++) {
    aDst[i] = aT + (i * 4 + wave) * 512;
    bDst[i] = bT + (i * 4 + wave) * 512;
  }
  // ---- hoisted LDS read base pointers (colA has exactly 2 values; the
  //      i*1024 / j*1024 element steps fold into ds_read offset: immediates)
  const u16* pA[2];
  const u16* pB[2];
  #pragma unroll
  for (int h = 0; h < 2; h++) {
    const int colA = ((h * 4 + q4) ^ swz) << 3;
    pA[h] = aT + (wm + l15) * 64 + colA;
    pB[h] = bT + (wn + l15) * 64 + colA;
  }

  f32x4 zero4 = {0.f, 0.f, 0.f, 0.f};
  f32x4 acc[4][4];
  #pragma unroll
  for (int i = 0; i < 4; i++)
    #pragma unroll
    for (int j = 0; j < 4; j++) acc[i][j] = zero4;

  const int nk = K >> 6;
  for (int t = 0; t < nk; ++t) {
    __syncthreads();  // prior compute done -> LDS reusable
    #pragma unroll
    for (int i = 0; i < 4; i++) {
      __builtin_amdgcn_global_load_lds(
          (const __attribute__((address_space(1))) unsigned*)aSrc[i],
          (__attribute__((address_space(3))) unsigned*)aDst[i], 16, 0, 0);
      __builtin_amdgcn_global_load_lds(
          (const __attribute__((address_space(1))) unsigned*)bSrc[i],
          (__attribute__((address_space(3))) unsigned*)bDst[i], 16, 0, 0);
      aSrc[i] += 64;
      bSrc[i] += 64;
    }
    __syncthreads();  // tile resident (drain covered by other resident blocks)
    #pragma unroll
    for (int h = 0; h < 2; h++) {
      s16x8 fb[4], fa[4];
      #pragma unroll
      for (int j = 0; j < 4; j++)
        fb[j] = *(const s16x8*)(pB[h] + j * 1024);
      #pragma unroll
      for (int i = 0; i < 4; i++)
        fa[i] = *(const s16x8*)(pA[h] + i * 1024);
      #pragma unroll
      for (int i = 0; i < 4; i++)
        #pragma unroll
        for (int j = 0; j < 4; j++) {
          if (MODE == 1)   // original: reg r -> row wm+i*16+q4*4+r, col wn+j*16+l15
            acc[i][j] = __builtin_amdgcn_mfma_f32_16x16x32_bf16(fa[i], fb[j], acc[i][j], 0, 0, 0);
          else             // swapped:  reg r -> row wm+i*16+l15, col wn+j*16+q4*4+r
            acc[i][j] = __builtin_amdgcn_mfma_f32_16x16x32_bf16(fb[j], fa[i], acc[i][j], 0, 0, 0);
        }
    }
  }

  if (MODE == 1) {
    // ---- round-6 coalesced epilogue: f32 RMW via LDS, two 64-row passes ----
    __syncthreads();  // all waves done reading staging LDS
    float* sf = (float*)smem;
    #pragma unroll
    for (int p = 0; p < 2; ++p) {
      if ((wm >> 6) == p) {
        #pragma unroll
        for (int i = 0; i < 4; i++)
          #pragma unroll
          for (int j = 0; j < 4; j++) {
            int lc = wn + j * 16 + l15;
            float bv = bias[n0 + lc];
            #pragma unroll
            for (int r = 0; r < 4; r++)
              sf[(i * 16 + q4 * 4 + r) * 132 + lc] = acc[i][j][r] + bv;
          }
      }
      __syncthreads();
      #pragma unroll
      for (int s = 0; s < 8; ++s) {
        int idx = s * 256 + tid;        // 0..2047
        int row = idx >> 5;             // 0..63
        int c4 = (idx & 31) * 4;        // f32 col, 0..124
        float* gp = resid + (size_t)(m0 + p * 64 + row) * N + n0 + c4;
        float4 t = *(float4*)gp;
        float4 l = *(const float4*)&sf[row * 132 + c4];
        t.x += l.x; t.y += l.y; t.z += l.z; t.w += l.w;
        *(float4*)gp = t;
      }
      __syncthreads();
    }
  } else {
    // ---- direct vector epilogue (no LDS, no barriers), swapped layout ----
    #pragma unroll
    for (int j = 0; j < 4; j++) {
      const int gn0 = n0 + wn + j * 16 + q4 * 4;
      const float4 bv = *(const float4*)&bias[gn0];
      #pragma unroll
      for (int i = 0; i < 4; i++) {
        const int gm = m0 + wm + i * 16 + l15;
        float v0 = acc[i][j][0] + bv.x;
        float v1 = acc[i][j][1] + bv.y;
        float v2 = acc[i][j][2] + bv.z;
        float v3 = acc[i][j][3] + bv.w;
        if (MODE == 2) {
          v0 = gelu_exact(v0); v1 = gelu_exact(v1);
          v2 = gelu_exact(v2); v3 = gelu_exact(v3);
        }
        uint2 pk;
        pk.x = (unsigned)f2bfu(v0) | ((unsigned)f2bfu(v1) << 16);
        pk.y = (unsigned)f2bfu(v2) | ((unsigned)f2bfu(v3) << 16);
        *(uint2*)(outb + (size_t)gm * N + gn0) = pk;
      }
    }
  }
}

// ---------------- fused attention per (b,h): 2 waves/block ----------------
__global__ __launch_bounds__(128) void attn_kernel(
    const u16* __restrict__ qkv, const unsigned char* __restrict__ maskb,
    u16* __restrict__ attnb) {
  __shared__ u16 vt_s[2][MTOK * 72];
  __shared__ u16 sP_s[2][MTOK * 72];
  __shared__ float maskf[MTOK];

  const int tid = threadIdx.x;
  const int wave = tid >> 6, lane = tid & 63;
  const int l15 = lane & 15, q4 = lane >> 4;
  const int b = blockIdx.x >> 2;
  const int h = ((blockIdx.x & 3) << 1) + wave;
  u16* vtw = vt_s[wave];
  u16* sw = sP_s[wave];

  if (tid < MTOK) maskf[tid] = maskb[b * MTOK + tid] ? 0.0f : -1e9f;

  {
    const u16* vrow = qkv + (size_t)(b * MTOK + lane) * 1536 + 1024 + h * HDIM;
    #pragma unroll
    for (int c8 = 0; c8 < 8; ++c8) {
      s16x8 v8 = *(const s16x8*)(vrow + c8 * 8);
      #pragma unroll
      for (int e = 0; e < 8; ++e)
        vtw[(c8 * 8 + e) * 72 + lane] = (u16)v8[e];
    }
  }
  __syncthreads();

  f32x4 zero4 = {0.f, 0.f, 0.f, 0.f};
  f32x4 acc[4][4];
  #pragma unroll
  for (int i = 0; i < 4; i++)
    #pragma unroll
    for (int j = 0; j < 4; j++) acc[i][j] = zero4;

  const u16* qbase = qkv + h * HDIM;
  const u16* kbase = qkv + 512 + h * HDIM;
  #pragma unroll
  for (int kk = 0; kk < HDIM; kk += 32) {
    s16x8 fa[4], fb[4];
    #pragma unroll
    for (int t = 0; t < 4; t++) {
      fa[t] = *(const s16x8*)(qbase + (size_t)(b * MTOK + t * 16 + l15) * 1536 + kk + q4 * 8);
      fb[t] = *(const s16x8*)(kbase + (size_t)(b * MTOK + t * 16 + l15) * 1536 + kk + q4 * 8);
    }
    #pragma unroll
    for (int i = 0; i < 4; i++)
      #pragma unroll
      for (int j = 0; j < 4; j++)
        acc[i][j] = __builtin_amdgcn_mfma_f32_16x16x32_bf16(fa[i], fb[j], acc[i][j], 0, 0, 0);
  }

  float mk[4];
  #pragma unroll
  for (int j = 0; j < 4; j++) mk[j] = maskf[j * 16 + l15];

  #pragma unroll
  for (int i = 0; i < 4; i++) {
    #pragma unroll
    for (int r = 0; r < 4; r++) {
      float mx = -3.0e38f;
      #pragma unroll
      for (int j = 0; j < 4; j++) {
        float s = acc[i][j][r] * 0.125f + mk[j];
        acc[i][j][r] = s;
        mx = fmaxf(mx, s);
      }
      mx = fmaxf(mx, __shfl_xor(mx, 1));
      mx = fmaxf(mx, __shfl_xor(mx, 2));
      mx = fmaxf(mx, __shfl_xor(mx, 4));
      mx = fmaxf(mx, __shfl_xor(mx, 8));
      float sum = 0.f;
      #pragma unroll
      for (int j = 0; j < 4; j++) {
        float e = __expf(acc[i][j][r] - mx);
        acc[i][j][r] = e;
        sum += e;
      }
      sum += __shfl_xor(sum, 1);
      sum += __shfl_xor(sum, 2);
      sum += __shfl_xor(sum, 4);
      sum += __shfl_xor(sum, 8);
      float inv = 1.0f / sum;
      int row = i * 16 + q4 * 4 + r;
      #pragma unroll
      for (int j = 0; j < 4; j++)
        sw[row * 72 + j * 16 + l15] = f2bfu(acc[i][j][r] * inv);
    }
  }
  __syncthreads();

  f32x4 oacc[4][4];
  #pragma unroll
  for (int i = 0; i < 4; i++)
    #pragma unroll
    for (int j = 0; j < 4; j++) oacc[i][j] = zero4;
  #pragma unroll
  for (int kk = 0; kk < MTOK; kk += 32) {
    s16x8 fa[4], fb[4];
    #pragma unroll
    for (int t = 0; t < 4; t++) {
      fa[t] = *(const s16x8*)(sw + (t * 16 + l15) * 72 + kk + q4 * 8);
      fb[t] = *(const s16x8*)(vtw + (t * 16 + l15) * 72 + kk + q4 * 8);
    }
    #pragma unroll
    for (int i = 0; i < 4; i++)
      #pragma unroll
      for (int j = 0; j < 4; j++)
        oacc[i][j] = __builtin_amdgcn_mfma_f32_16x16x32_bf16(fa[i], fb[j], oacc[i][j], 0, 0, 0);
  }
  #pragma unroll
  for (int i = 0; i < 4; i++)
    #pragma unroll
    for (int j = 0; j < 4; j++)
      #pragma unroll
      for (int r = 0; r < 4; r++)
        attnb[(size_t)(b * MTOK + i * 16 + q4 * 4 + r) * DM + h * HDIM + j * 16 + l15] =
            f2bfu(oacc[i][j][r]);
}

// ---------------- host ----------------
extern "C" void kernel_launch(void* const* d_in, const int* in_sizes, int n_in,
                              void* d_out, int out_size, void* d_ws, size_t ws_size,
                              hipStream_t stream) {
  (void)in_sizes; (void)n_in; (void)out_size; (void)ws_size;

  const int*   objs     = (const int*)  d_in[0];
  const float* boxes    = (const float*)d_in[1];
  const int*   triples  = (const int*)  d_in[2];
  const int*   tti      = (const int*)  d_in[4];
  const float* obj_emb  = (const float*)d_in[5];
  const float* pred_emb = (const float*)d_in[6];
  const float* bw1      = (const float*)d_in[7];
  const float* bb1      = (const float*)d_in[8];
  const float* blg      = (const float*)d_in[9];
  const float* blb      = (const float*)d_in[10];
  const float* bw2      = (const float*)d_in[11];
  const float* bb2      = (const float*)d_in[12];
  const float* ln1g     = (const float*)d_in[13];
  const float* ln1b     = (const float*)d_in[14];
  const float* wq       = (const float*)d_in[15];
  const float* bq       = (const float*)d_in[16];
  const float* wk       = (const float*)d_in[17];
  const float* bk       = (const float*)d_in[18];
  const float* wv       = (const float*)d_in[19];
  const float* bv       = (const float*)d_in[20];
  const float* wo       = (const float*)d_in[21];
  const float* bo       = (const float*)d_in[22];
  const float* ln2g     = (const float*)d_in[23];
  const float* ln2b     = (const float*)d_in[24];
  const float* wf1      = (const float*)d_in[25];
  const float* bf1      = (const float*)d_in[26];
  const float* wf2      = (const float*)d_in[27];
  const float* bf2      = (const float*)d_in[28];

  float* x = (float*)d_out;  // residual stream lives in d_out (B*MT x D, f32)

  char* w = (char*)d_ws;
  u16* h_bf    = (u16*)w;   w += 67108864;      // 65536*512 bf16
  u16* big     = (u16*)w;   w += 268435456;     // qkv(201MB)+attn(67MB) OR ff1(268MB)
  float* obj_tok = (float*)w; w += 16777216;    // 8192*512 f32
  u16* wqkvt   = (u16*)w;   w += 6291456;       // 4*1536*512 bf16
  u16* wot     = (u16*)w;   w += 2097152;       // 4*512*512 bf16
  u16* wf1t    = (u16*)w;   w += 8388608;       // 4*2048*512 bf16
  u16* wf2t    = (u16*)w;   w += 8388608;       // 4*512*2048 bf16
  float* bqkv  = (float*)w; w += 24576;         // 4*1536 f32
  int* first   = (int*)w;   w += 4096;
  unsigned char* maskb = (unsigned char*)w; w += 65536;

  u16* qkv_bf  = big;
  u16* attn_bf = big + 100663296UL;  // 65536*1536
  u16* ff1_bf  = big;

  hipMemsetAsync(x, 0, 134217728UL, stream);
  hipMemsetAsync(maskb, 0, 65536, stream);

  transpose_dd_kernel<<<dim3(16, 16, 16), dim3(32, 8), 0, stream>>>(wq, wk, wv, wo, wqkvt, wot);
  transpose_gen_kernel<<<dim3(64, 16, 4), dim3(32, 8), 0, stream>>>(wf1, wf1t, 512, 2048);
  transpose_gen_kernel<<<dim3(16, 64, 4), dim3(32, 8), 0, stream>>>(wf2, wf2t, 2048, 512);
  concat_bias_kernel<<<24, 256, 0, stream>>>(bq, bk, bv, bqkv);
  first_kernel<<<1, 1024, 0, stream>>>(tti, first);
  boxmlp_kernel<<<512, 256, 0, stream>>>(objs, boxes, bw1, bb1, blg, blb, bw2, bb2, obj_emb, obj_tok);
  scatter_kernel<<<NTRI * 3, 128, 0, stream>>>(triples, tti, first, obj_tok, pred_emb, x, maskb);

  // grids: M/128 = 512 row-panels; 1-D grid = 512 * nb_n  (nb_n = N/128)
  for (int l = 0; l < 4; l++) {
    ln_kernel<<<16384, 256, 0, stream>>>(x, h_bf, ln1g + l * 512, ln1b + l * 512);
    gemm_kernel<0><<<512 * 12, 256, 0, stream>>>(h_bf, wqkvt + (size_t)l * 786432,
                                                 bqkv + l * 1536, nullptr, qkv_bf,
                                                 65536, 1536, 512, 12);
    attn_kernel<<<4096, 128, 0, stream>>>(qkv_bf, maskb, attn_bf);
    gemm_kernel<1><<<512 * 4, 256, 0, stream>>>(attn_bf, wot + (size_t)l * 262144,
                                                bo + l * 512, x, nullptr,
                                                65536, 512, 512, 4);
    ln_kernel<<<16384, 256, 0, stream>>>(x, h_bf, ln2g + l * 512, ln2b + l * 512);
    gemm_kernel<2><<<512 * 16, 256, 0, stream>>>(h_bf, wf1t + (size_t)l * 1048576,
                                                 bf1 + l * 2048, nullptr, ff1_bf,
                                                 65536, 2048, 512, 16);
    gemm_kernel<1><<<512 * 4, 256, 0, stream>>>(ff1_bf, wf2t + (size_t)l * 1048576,
                                                bf2 + l * 512, x, nullptr,
                                                65536, 512, 2048, 4);
  }
}

// Round 12
// 3313.932 us; speedup vs baseline: 1.0542x; 1.0542x over previous
//
#include <hip/hip_runtime.h>

typedef unsigned short u16;
typedef __attribute__((ext_vector_type(8))) short s16x8;
typedef __attribute__((ext_vector_type(4))) float f32x4;

#define NB    1024
#define MTOK  64
#define DM    512
#define NHD   8
#define HDIM  64
#define FFD   2048
#define NOBJ  8192
#define NTRI  10240

__device__ __forceinline__ float bfu2f(u16 u) { return __uint_as_float(((unsigned)u) << 16); }
__device__ __forceinline__ u16 f2bfu(float f) {
  unsigned u = __float_as_uint(f);
  u += 0x7FFFu + ((u >> 16) & 1u);
  return (u16)(u >> 16);
}
// tanh-form gelu (jax approximate=True): 0.5x(1+tanh(0.7978845608(x+0.044715x^3))).
// Max |diff| vs exact erf-gelu ~3.3e-4 — an order below bf16 rounding at the
// magnitudes seen here (|x| <~ 3). 10 straight-line ops, 1 exp, 1 rcp.
// tanh via 1 - 2/(1+exp2(2.885390082*y)): inf-safe (t=inf -> rcp=0 -> tanh=1).
__device__ __forceinline__ float gelu_exact(float x) {
  float x2 = x * x;
  float inner = x * __builtin_fmaf(x2, 0.044715f, 1.0f);      // x + 0.044715x^3
  float t = __builtin_amdgcn_exp2f(inner * 2.302118131f);     // exp2(2*1.4427*0.79788*inner)
  float th = __builtin_fmaf(-2.0f, __builtin_amdgcn_rcpf(1.0f + t), 1.0f);
  float hx = 0.5f * x;
  return __builtin_fmaf(th, hx, hx);                          // 0.5x(1+tanh)
}

// ---------------- weight prep: f32 [R][C] -> bf16 [C][R] ----------------
__global__ void transpose_dd_kernel(const float* __restrict__ wq, const float* __restrict__ wk,
                                    const float* __restrict__ wv, const float* __restrict__ wo,
                                    u16* __restrict__ wqkvt, u16* __restrict__ wot) {
  __shared__ u16 tile[32][33];
  int l = blockIdx.z >> 2, w = blockIdx.z & 3;
  const float* src = (w == 0 ? wq : w == 1 ? wk : w == 2 ? wv : wo) + (size_t)l * 262144;
  u16* dst = (w < 3) ? (wqkvt + (size_t)l * 786432 + (size_t)w * 262144) : (wot + (size_t)l * 262144);
  int c0 = blockIdx.x * 32, r0 = blockIdx.y * 32;
  int tx = threadIdx.x, ty = threadIdx.y;
  #pragma unroll
  for (int i = 0; i < 4; i++)
    tile[ty + i * 8][tx] = f2bfu(src[(size_t)(r0 + ty + i * 8) * 512 + c0 + tx]);
  __syncthreads();
  #pragma unroll
  for (int i = 0; i < 4; i++)
    dst[(size_t)(c0 + ty + i * 8) * 512 + r0 + tx] = tile[tx][ty + i * 8];
}

__global__ void transpose_gen_kernel(const float* __restrict__ src, u16* __restrict__ dst,
                                     int R, int C) {
  __shared__ u16 tile[32][33];
  size_t mat = blockIdx.z;
  const float* s = src + mat * (size_t)R * C;
  u16* d = dst + mat * (size_t)R * C;
  int c0 = blockIdx.x * 32, r0 = blockIdx.y * 32;
  int tx = threadIdx.x, ty = threadIdx.y;
  #pragma unroll
  for (int i = 0; i < 4; i++)
    tile[ty + i * 8][tx] = f2bfu(s[(size_t)(r0 + ty + i * 8) * C + c0 + tx]);
  __syncthreads();
  #pragma unroll
  for (int i = 0; i < 4; i++)
    d[(size_t)(c0 + ty + i * 8) * R + r0 + tx] = tile[tx][ty + i * 8];
}

__global__ void concat_bias_kernel(const float* __restrict__ bq, const float* __restrict__ bk,
                                   const float* __restrict__ bv, float* __restrict__ bqkv) {
  int i = blockIdx.x * 256 + threadIdx.x;  // < 4*1536
  int l = i / 1536, j = i - l * 1536;
  int w = j >> 9, d = j & 511;
  const float* s = (w == 0) ? bq : (w == 1 ? bk : bv);
  bqkv[i] = s[l * 512 + d];
}

// ---------------- first[b] = lower_bound(triple_to_img, b) ----------------
__global__ void first_kernel(const int* __restrict__ tti, int* __restrict__ first) {
  int b = threadIdx.x;  // 1024 threads
  int lo = 0, hi = NTRI;
  while (lo < hi) { int mid = (lo + hi) >> 1; if (tti[mid] < b) lo = mid + 1; else hi = mid; }
  first[b] = lo;
}

// ---------------- box MLP + embedding: obj_tok (f32) ----------------
__global__ __launch_bounds__(256) void boxmlp_kernel(
    const int* __restrict__ objs, const float* __restrict__ boxes,
    const float* __restrict__ bw1, const float* __restrict__ bb1,
    const float* __restrict__ blg, const float* __restrict__ blb,
    const float* __restrict__ bw2, const float* __restrict__ bb2,
    const float* __restrict__ obj_emb, float* __restrict__ obj_tok) {
  __shared__ float hbuf[16][512];
  int tid = threadIdx.x;
  int base = blockIdx.x * 16;
  for (int o = 0; o < 16; o++) {
    int obj = base + o;
    float b0 = boxes[obj * 4 + 0], b1 = boxes[obj * 4 + 1];
    float b2 = boxes[obj * 4 + 2], b3 = boxes[obj * 4 + 3];
    for (int d = tid; d < 512; d += 256)
      hbuf[o][d] = bb1[d] + b0 * bw1[d] + b1 * bw1[512 + d] + b2 * bw1[1024 + d] + b3 * bw1[1536 + d];
  }
  __syncthreads();
  int wave = tid >> 6, lane = tid & 63;
  for (int oo = 0; oo < 4; oo++) {
    int o = wave * 4 + oo;
    float v[8], s = 0.f, ss = 0.f;
    #pragma unroll
    for (int e = 0; e < 8; e++) { v[e] = hbuf[o][lane * 8 + e]; s += v[e]; ss += v[e] * v[e]; }
    for (int off = 32; off > 0; off >>= 1) { s += __shfl_xor(s, off); ss += __shfl_xor(ss, off); }
    float mean = s * (1.0f / 512.0f);
    float var = ss * (1.0f / 512.0f) - mean * mean;
    float rstd = rsqrtf(var + 1e-5f);
    #pragma unroll
    for (int e = 0; e < 8; e++) {
      int d = lane * 8 + e;
      float g = (v[e] - mean) * rstd * blg[d] + blb[d];
      hbuf[o][d] = gelu_exact(g);
    }
  }
  __syncthreads();
  float acc0[16], acc1[16];
  #pragma unroll
  for (int o = 0; o < 16; o++) { acc0[o] = 0.f; acc1[o] = 0.f; }
  int d0 = tid, d1 = tid + 256;
  for (int k = 0; k < 512; k += 4) {
    float w0[4], w1[4];
    #pragma unroll
    for (int kk = 0; kk < 4; kk++) { w0[kk] = bw2[(k + kk) * 512 + d0]; w1[kk] = bw2[(k + kk) * 512 + d1]; }
    #pragma unroll
    for (int o = 0; o < 16; o++) {
      float4 hv = *(const float4*)&hbuf[o][k];
      acc0[o] += hv.x * w0[0] + hv.y * w0[1] + hv.z * w0[2] + hv.w * w0[3];
      acc1[o] += hv.x * w1[0] + hv.y * w1[1] + hv.z * w1[2] + hv.w * w1[3];
    }
  }
  #pragma unroll
  for (int o = 0; o < 16; o++) {
    int obj = base + o;
    int e = objs[obj];
    obj_tok[(size_t)obj * 512 + d0] = acc0[o] + bb2[d0] + obj_emb[(size_t)e * 512 + d0];
    obj_tok[(size_t)obj * 512 + d1] = acc1[o] + bb2[d1] + obj_emb[(size_t)e * 512 + d1];
  }
}

// ---------------- scatter triples -> tokens (x) + mask ----------------
__global__ __launch_bounds__(128) void scatter_kernel(
    const int* __restrict__ triples, const int* __restrict__ tti,
    const int* __restrict__ first, const float* __restrict__ obj_tok,
    const float* __restrict__ pred_emb, float* __restrict__ x,
    unsigned char* __restrict__ maskb) {
  int t = blockIdx.x / 3, j = blockIdx.x - t * 3;
  int b = tti[t];
  int pos = t - first[b];
  int slot = pos * 3 + j;
  if (slot >= MTOK) return;
  int dst_row = b * MTOK + slot;
  int d = threadIdx.x * 4;
  float4 val;
  if (j == 1) {
    int p = triples[t * 3 + 1];
    val = *(const float4*)(pred_emb + (size_t)p * 512 + d);
  } else {
    int oi = triples[t * 3 + (j == 0 ? 0 : 2)];
    val = *(const float4*)(obj_tok + (size_t)oi * 512 + d);
  }
  *(float4*)(x + (size_t)dst_row * 512 + d) = val;
  if (threadIdx.x == 0) maskb[dst_row] = 1;
}

// ---------------- LayerNorm (f32 in) -> bf16 out ----------------
__global__ __launch_bounds__(256) void ln_kernel(
    const float* __restrict__ x, u16* __restrict__ out,
    const float* __restrict__ gg, const float* __restrict__ bb) {
  int row = blockIdx.x * 4 + (threadIdx.x >> 6);
  int lane = threadIdx.x & 63;
  const float* xr = x + (size_t)row * DM + lane * 8;
  float4 a = *(const float4*)xr;
  float4 c = *(const float4*)(xr + 4);
  float v[8] = {a.x, a.y, a.z, a.w, c.x, c.y, c.z, c.w};
  float s = 0.f, ss = 0.f;
  #pragma unroll
  for (int e = 0; e < 8; e++) { s += v[e]; ss += v[e] * v[e]; }
  for (int off = 32; off > 0; off >>= 1) { s += __shfl_xor(s, off); ss += __shfl_xor(ss, off); }
  float mean = s * (1.0f / 512.0f);
  float var = ss * (1.0f / 512.0f) - mean * mean;
  float rstd = rsqrtf(var + 1e-5f);
  int dbase = lane * 8;
  unsigned pk[4];
  #pragma unroll
  for (int p = 0; p < 4; p++) {
    float y0 = (v[2 * p] - mean) * rstd * gg[dbase + 2 * p] + bb[dbase + 2 * p];
    float y1 = (v[2 * p + 1] - mean) * rstd * gg[dbase + 2 * p + 1] + bb[dbase + 2 * p + 1];
    pk[p] = (unsigned)f2bfu(y0) | ((unsigned)f2bfu(y1) << 16);
  }
  uint4 o; o.x = pk[0]; o.y = pk[1]; o.z = pk[2]; o.w = pk[3];
  *(uint4*)(out + (size_t)row * DM + dbase) = o;
}

// ---------------- bf16 MFMA GEMM: per-mode MEASURED-BEST epilogues.
// Round-12 consolidation (within-run per-dispatch evidence, rounds 6-11):
//  MODE 0 (QKV, bf16 out, no gelu): round-6 single-pass coalesced LDS
//    roundtrip (16B stores) — QKV has no gelu so roundtrip VALU is trivial;
//    direct 8B scattered stores were the suspected hidden regression.
//  MODE 1 (f32 resid RMW): round-6 two-pass coalesced roundtrip (measured
//    best; direct scattered RMW cost FF2 +28us in round 9).
//  MODE 2 (FF1, gelu+bf16 out): SWAPPED operands + direct uint2 stores
//    (measured best: 217-221 vs 238-243 roundtrip) + cheaper tanh-gelu
//    (FF1 VALUBusy 48% is the gelu epilogue; K=512 gives only 1024
//    FLOP/output of amortization, so epilogue ops/output matter).
// K-loop: hoisted addressing (round 11, neutral), 128x128 tile, BK=64,
// single-buffered staging, 256 thr / 4 waves, launch_bounds(256,4)
// [(256,5) spilled: round 7]. C = A[MxK] @ Wt[NxK]^T (+bias)
// MODE 0: outb = bf16(acc+bias)  MODE 1: resid += acc+bias  MODE 2: outb = bf16(gelu(acc+bias))
template <int MODE>
__global__ __launch_bounds__(256, 4) void gemm_kernel(
    const u16* __restrict__ A, const u16* __restrict__ Wt,
    const float* __restrict__ bias, float* __restrict__ resid,
    u16* __restrict__ outb, int M, int N, int K, int nb_n) {
  // MODE 0: 128x136 u16 = 34,816B; MODE 1: 64x132 f32 = 33,792B; MODE 2: 32KB.
  __shared__ __align__(16) u16 smem[MODE == 2 ? 16384 : 17408];
  u16* aT = smem;          // 128x64 u16 = 16 KB
  u16* bT = smem + 8192;   // 128x64 u16 = 16 KB
  const int tid = threadIdx.x;
  const int wave = tid >> 6, lane = tid & 63;
  const int l15 = lane & 15, q4 = lane >> 4;
  const int wm = (wave >> 1) * 64, wn = (wave & 1) * 64;

  const int L = blockIdx.x;
  const int xg = L & 7, g = L >> 3;
  const int cblk = g % nb_n;
  const int pblk = xg + 8 * (g / nb_n);
  const int m0 = pblk * 128;
  const int n0 = cblk * 128;

  const int lrow = lane >> 3;                       // 0..7
  const int scol = (((lane & 7) ^ lrow) << 3);      // swizzled source col
  const int swz = l15 & 7;                          // fragment-read swizzle

  // ---- hoisted staging source pointers (advance 64 u16 = 128B per K-step)
  const u16* aSrc[4];
  const u16* bSrc[4];
  #pragma unroll
  for (int i = 0; i < 4; i++) {
    const int chunk = i * 4 + wave;
    const int row = chunk * 8 + lrow;
    aSrc[i] = A + (size_t)(m0 + row) * K + scol;
    bSrc[i] = Wt + (size_t)(n0 + row) * K + scol;
  }
  u16* aDst[4];
  u16* bDst[4];
  #pragma unroll
  for (int i = 0; i < 4; i++) {
    aDst[i] = aT + (i * 4 + wave) * 512;
    bDst[i] = bT + (i * 4 + wave) * 512;
  }
  const u16* pA[2];
  const u16* pB[2];
  #pragma unroll
  for (int h = 0; h < 2; h++) {
    const int colA = ((h * 4 + q4) ^ swz) << 3;
    pA[h] = aT + (wm + l15) * 64 + colA;
    pB[h] = bT + (wn + l15) * 64 + colA;
  }

  f32x4 zero4 = {0.f, 0.f, 0.f, 0.f};
  f32x4 acc[4][4];
  #pragma unroll
  for (int i = 0; i < 4; i++)
    #pragma unroll
    for (int j = 0; j < 4; j++) acc[i][j] = zero4;

  const int nk = K >> 6;
  for (int t = 0; t < nk; ++t) {
    __syncthreads();  // prior compute done -> LDS reusable
    #pragma unroll
    for (int i = 0; i < 4; i++) {
      __builtin_amdgcn_global_load_lds(
          (const __attribute__((address_space(1))) unsigned*)aSrc[i],
          (__attribute__((address_space(3))) unsigned*)aDst[i], 16, 0, 0);
      __builtin_amdgcn_global_load_lds(
          (const __attribute__((address_space(1))) unsigned*)bSrc[i],
          (__attribute__((address_space(3))) unsigned*)bDst[i], 16, 0, 0);
      aSrc[i] += 64;
      bSrc[i] += 64;
    }
    __syncthreads();  // tile resident (drain covered by other resident blocks)
    #pragma unroll
    for (int h = 0; h < 2; h++) {
      s16x8 fb[4], fa[4];
      #pragma unroll
      for (int j = 0; j < 4; j++)
        fb[j] = *(const s16x8*)(pB[h] + j * 1024);
      #pragma unroll
      for (int i = 0; i < 4; i++)
        fa[i] = *(const s16x8*)(pA[h] + i * 1024);
      #pragma unroll
      for (int i = 0; i < 4; i++)
        #pragma unroll
        for (int j = 0; j < 4; j++) {
          if (MODE == 2)   // swapped:  reg r -> row wm+i*16+l15, col wn+j*16+q4*4+r
            acc[i][j] = __builtin_amdgcn_mfma_f32_16x16x32_bf16(fb[j], fa[i], acc[i][j], 0, 0, 0);
          else             // original: reg r -> row wm+i*16+q4*4+r, col wn+j*16+l15
            acc[i][j] = __builtin_amdgcn_mfma_f32_16x16x32_bf16(fa[i], fb[j], acc[i][j], 0, 0, 0);
        }
    }
  }

  if (MODE == 0) {
    // ---- round-6 coalesced epilogue: bf16 out via LDS, single pass ----
    __syncthreads();  // all waves done reading staging LDS
    #pragma unroll
    for (int i = 0; i < 4; i++)
      #pragma unroll
      for (int j = 0; j < 4; j++) {
        int lc = wn + j * 16 + l15;
        float bv = bias[n0 + lc];
        #pragma unroll
        for (int r = 0; r < 4; r++)
          smem[(wm + i * 16 + q4 * 4 + r) * 136 + lc] = f2bfu(acc[i][j][r] + bv);
      }
    __syncthreads();
    const int c8 = (tid & 15) * 8;   // u16 col 0..120
    const int r4 = tid >> 4;         // 0..15
    #pragma unroll
    for (int s = 0; s < 8; ++s) {
      int row = s * 16 + r4;
      s16x8 val = *(const s16x8*)&smem[row * 136 + c8];
      *(s16x8*)(outb + (size_t)(m0 + row) * N + n0 + c8) = val;
    }
  } else if (MODE == 1) {
    // ---- round-6 coalesced epilogue: f32 RMW via LDS, two 64-row passes ----
    __syncthreads();  // all waves done reading staging LDS
    float* sf = (float*)smem;
    #pragma unroll
    for (int p = 0; p < 2; ++p) {
      if ((wm >> 6) == p) {
        #pragma unroll
        for (int i = 0; i < 4; i++)
          #pragma unroll
          for (int j = 0; j < 4; j++) {
            int lc = wn + j * 16 + l15;
            float bv = bias[n0 + lc];
            #pragma unroll
            for (int r = 0; r < 4; r++)
              sf[(i * 16 + q4 * 4 + r) * 132 + lc] = acc[i][j][r] + bv;
          }
      }
      __syncthreads();
      #pragma unroll
      for (int s = 0; s < 8; ++s) {
        int idx = s * 256 + tid;        // 0..2047
        int row = idx >> 5;             // 0..63
        int c4 = (idx & 31) * 4;        // f32 col, 0..124
        float* gp = resid + (size_t)(m0 + p * 64 + row) * N + n0 + c4;
        float4 t = *(float4*)gp;
        float4 l = *(const float4*)&sf[row * 132 + c4];
        t.x += l.x; t.y += l.y; t.z += l.z; t.w += l.w;
        *(float4*)gp = t;
      }
      __syncthreads();
    }
  } else {
    // ---- direct vector epilogue (no LDS, no barriers), swapped layout ----
    #pragma unroll
    for (int j = 0; j < 4; j++) {
      const int gn0 = n0 + wn + j * 16 + q4 * 4;
      const float4 bv = *(const float4*)&bias[gn0];
      #pragma unroll
      for (int i = 0; i < 4; i++) {
        const int gm = m0 + wm + i * 16 + l15;
        float v0 = gelu_exact(acc[i][j][0] + bv.x);
        float v1 = gelu_exact(acc[i][j][1] + bv.y);
        float v2 = gelu_exact(acc[i][j][2] + bv.z);
        float v3 = gelu_exact(acc[i][j][3] + bv.w);
        uint2 pk;
        pk.x = (unsigned)f2bfu(v0) | ((unsigned)f2bfu(v1) << 16);
        pk.y = (unsigned)f2bfu(v2) | ((unsigned)f2bfu(v3) << 16);
        *(uint2*)(outb + (size_t)gm * N + gn0) = pk;
      }
    }
  }
}

// ---------------- fused attention per (b,h): 2 waves/block ----------------
__global__ __launch_bounds__(128) void attn_kernel(
    const u16* __restrict__ qkv, const unsigned char* __restrict__ maskb,
    u16* __restrict__ attnb) {
  __shared__ u16 vt_s[2][MTOK * 72];
  __shared__ u16 sP_s[2][MTOK * 72];
  __shared__ float maskf[MTOK];

  const int tid = threadIdx.x;
  const int wave = tid >> 6, lane = tid & 63;
  const int l15 = lane & 15, q4 = lane >> 4;
  const int b = blockIdx.x >> 2;
  const int h = ((blockIdx.x & 3) << 1) + wave;
  u16* vtw = vt_s[wave];
  u16* sw = sP_s[wave];

  if (tid < MTOK) maskf[tid] = maskb[b * MTOK + tid] ? 0.0f : -1e9f;

  {
    const u16* vrow = qkv + (size_t)(b * MTOK + lane) * 1536 + 1024 + h * HDIM;
    #pragma unroll
    for (int c8 = 0; c8 < 8; ++c8) {
      s16x8 v8 = *(const s16x8*)(vrow + c8 * 8);
      #pragma unroll
      for (int e = 0; e < 8; ++e)
        vtw[(c8 * 8 + e) * 72 + lane] = (u16)v8[e];
    }
  }
  __syncthreads();

  f32x4 zero4 = {0.f, 0.f, 0.f, 0.f};
  f32x4 acc[4][4];
  #pragma unroll
  for (int i = 0; i < 4; i++)
    #pragma unroll
    for (int j = 0; j < 4; j++) acc[i][j] = zero4;

  const u16* qbase = qkv + h * HDIM;
  const u16* kbase = qkv + 512 + h * HDIM;
  #pragma unroll
  for (int kk = 0; kk < HDIM; kk += 32) {
    s16x8 fa[4], fb[4];
    #pragma unroll
    for (int t = 0; t < 4; t++) {
      fa[t] = *(const s16x8*)(qbase + (size_t)(b * MTOK + t * 16 + l15) * 1536 + kk + q4 * 8);
      fb[t] = *(const s16x8*)(kbase + (size_t)(b * MTOK + t * 16 + l15) * 1536 + kk + q4 * 8);
    }
    #pragma unroll
    for (int i = 0; i < 4; i++)
      #pragma unroll
      for (int j = 0; j < 4; j++)
        acc[i][j] = __builtin_amdgcn_mfma_f32_16x16x32_bf16(fa[i], fb[j], acc[i][j], 0, 0, 0);
  }

  float mk[4];
  #pragma unroll
  for (int j = 0; j < 4; j++) mk[j] = maskf[j * 16 + l15];

  #pragma unroll
  for (int i = 0; i < 4; i++) {
    #pragma unroll
    for (int r = 0; r < 4; r++) {
      float mx = -3.0e38f;
      #pragma unroll
      for (int j = 0; j < 4; j++) {
        float s = acc[i][j][r] * 0.125f + mk[j];
        acc[i][j][r] = s;
        mx = fmaxf(mx, s);
      }
      mx = fmaxf(mx, __shfl_xor(mx, 1));
      mx = fmaxf(mx, __shfl_xor(mx, 2));
      mx = fmaxf(mx, __shfl_xor(mx, 4));
      mx = fmaxf(mx, __shfl_xor(mx, 8));
      float sum = 0.f;
      #pragma unroll
      for (int j = 0; j < 4; j++) {
        float e = __expf(acc[i][j][r] - mx);
        acc[i][j][r] = e;
        sum += e;
      }
      sum += __shfl_xor(sum, 1);
      sum += __shfl_xor(sum, 2);
      sum += __shfl_xor(sum, 4);
      sum += __shfl_xor(sum, 8);
      float inv = 1.0f / sum;
      int row = i * 16 + q4 * 4 + r;
      #pragma unroll
      for (int j = 0; j < 4; j++)
        sw[row * 72 + j * 16 + l15] = f2bfu(acc[i][j][r] * inv);
    }
  }
  __syncthreads();

  f32x4 oacc[4][4];
  #pragma unroll
  for (int i = 0; i < 4; i++)
    #pragma unroll
    for (int j = 0; j < 4; j++) oacc[i][j] = zero4;
  #pragma unroll
  for (int kk = 0; kk < MTOK; kk += 32) {
    s16x8 fa[4], fb[4];
    #pragma unroll
    for (int t = 0; t < 4; t++) {
      fa[t] = *(const s16x8*)(sw + (t * 16 + l15) * 72 + kk + q4 * 8);
      fb[t] = *(const s16x8*)(vtw + (t * 16 + l15) * 72 + kk + q4 * 8);
    }
    #pragma unroll
    for (int i = 0; i < 4; i++)
      #pragma unroll
      for (int j = 0; j < 4; j++)
        oacc[i][j] = __builtin_amdgcn_mfma_f32_16x16x32_bf16(fa[i], fb[j], oacc[i][j], 0, 0, 0);
  }
  #pragma unroll
  for (int i = 0; i < 4; i++)
    #pragma unroll
    for (int j = 0; j < 4; j++)
      #pragma unroll
      for (int r = 0; r < 4; r++)
        attnb[(size_t)(b * MTOK + i * 16 + q4 * 4 + r) * DM + h * HDIM + j * 16 + l15] =
            f2bfu(oacc[i][j][r]);
}

// ---------------- host ----------------
extern "C" void kernel_launch(void* const* d_in, const int* in_sizes, int n_in,
                              void* d_out, int out_size, void* d_ws, size_t ws_size,
                              hipStream_t stream) {
  (void)in_sizes; (void)n_in; (void)out_size; (void)ws_size;

  const int*   objs     = (const int*)  d_in[0];
  const float* boxes    = (const float*)d_in[1];
  const int*   triples  = (const int*)  d_in[2];
  const int*   tti      = (const int*)  d_in[4];
  const float* obj_emb  = (const float*)d_in[5];
  const float* pred_emb = (const float*)d_in[6];
  const float* bw1      = (const float*)d_in[7];
  const float* bb1      = (const float*)d_in[8];
  const float* blg      = (const float*)d_in[9];
  const float* blb      = (const float*)d_in[10];
  const float* bw2      = (const float*)d_in[11];
  const float* bb2      = (const float*)d_in[12];
  const float* ln1g     = (const float*)d_in[13];
  const float* ln1b     = (const float*)d_in[14];
  const float* wq       = (const float*)d_in[15];
  const float* bq       = (const float*)d_in[16];
  const float* wk       = (const float*)d_in[17];
  const float* bk       = (const float*)d_in[18];
  const float* wv       = (const float*)d_in[19];
  const float* bv       = (const float*)d_in[20];
  const float* wo       = (const float*)d_in[21];
  const float* bo       = (const float*)d_in[22];
  const float* ln2g     = (const float*)d_in[23];
  const float* ln2b     = (const float*)d_in[24];
  const float* wf1      = (const float*)d_in[25];
  const float* bf1      = (const float*)d_in[26];
  const float* wf2      = (const float*)d_in[27];
  const float* bf2      = (const float*)d_in[28];

  float* x = (float*)d_out;  // residual stream lives in d_out (B*MT x D, f32)

  char* w = (char*)d_ws;
  u16* h_bf    = (u16*)w;   w += 67108864;      // 65536*512 bf16
  u16* big     = (u16*)w;   w += 268435456;     // qkv(201MB)+attn(67MB) OR ff1(268MB)
  float* obj_tok = (float*)w; w += 16777216;    // 8192*512 f32
  u16* wqkvt   = (u16*)w;   w += 6291456;       // 4*1536*512 bf16
  u16* wot     = (u16*)w;   w += 2097152;       // 4*512*512 bf16
  u16* wf1t    = (u16*)w;   w += 8388608;       // 4*2048*512 bf16
  u16* wf2t    = (u16*)w;   w += 8388608;       // 4*512*2048 bf16
  float* bqkv  = (float*)w; w += 24576;         // 4*1536 f32
  int* first   = (int*)w;   w += 4096;
  unsigned char* maskb = (unsigned char*)w; w += 65536;

  u16* qkv_bf  = big;
  u16* attn_bf = big + 100663296UL;  // 65536*1536
  u16* ff1_bf  = big;

  hipMemsetAsync(x, 0, 134217728UL, stream);
  hipMemsetAsync(maskb, 0, 65536, stream);

  transpose_dd_kernel<<<dim3(16, 16, 16), dim3(32, 8), 0, stream>>>(wq, wk, wv, wo, wqkvt, wot);
  transpose_gen_kernel<<<dim3(64, 16, 4), dim3(32, 8), 0, stream>>>(wf1, wf1t, 512, 2048);
  transpose_gen_kernel<<<dim3(16, 64, 4), dim3(32, 8), 0, stream>>>(wf2, wf2t, 2048, 512);
  concat_bias_kernel<<<24, 256, 0, stream>>>(bq, bk, bv, bqkv);
  first_kernel<<<1, 1024, 0, stream>>>(tti, first);
  boxmlp_kernel<<<512, 256, 0, stream>>>(objs, boxes, bw1, bb1, blg, blb, bw2, bb2, obj_emb, obj_tok);
  scatter_kernel<<<NTRI * 3, 128, 0, stream>>>(triples, tti, first, obj_tok, pred_emb, x, maskb);

  // grids: M/128 = 512 row-panels; 1-D grid = 512 * nb_n  (nb_n = N/128)
  for (int l = 0; l < 4; l++) {
    ln_kernel<<<16384, 256, 0, stream>>>(x, h_bf, ln1g + l * 512, ln1b + l * 512);
    gemm_kernel<0><<<512 * 12, 256, 0, stream>>>(h_bf, wqkvt + (size_t)l * 786432,
                                                 bqkv + l * 1536, nullptr, qkv_bf,
                                                 65536, 1536, 512, 12);
    attn_kernel<<<4096, 128, 0, stream>>>(qkv_bf, maskb, attn_bf);
    gemm_kernel<1><<<512 * 4, 256, 0, stream>>>(attn_bf, wot + (size_t)l * 262144,
                                                bo + l * 512, x, nullptr,
                                                65536, 512, 512, 4);
    ln_kernel<<<16384, 256, 0, stream>>>(x, h_bf, ln2g + l * 512, ln2b + l * 512);
    gemm_kernel<2><<<512 * 16, 256, 0, stream>>>(h_bf, wf1t + (size_t)l * 1048576,
                                                 bf1 + l * 2048, nullptr, ff1_bf,
                                                 65536, 2048, 512, 16);
    gemm_kernel<1><<<512 * 4, 256, 0, stream>>>(ff1_bf, wf2t + (size_t)l * 1048576,
                                                bf2 + l * 512, x, nullptr,
                                                65536, 512, 2048, 4);
  }
}